// Round 1
// baseline (800.850 us; speedup 1.0000x reference)
//
#include <hip/hip_runtime.h>

typedef __attribute__((ext_vector_type(4))) float f32x4;
typedef __attribute__((ext_vector_type(8))) short bf16x8;
typedef __attribute__((ext_vector_type(8))) unsigned short u16x8;

#define GL2LDS(g, l) __builtin_amdgcn_global_load_lds( \
    (const __attribute__((address_space(1))) void*)(g), \
    (__attribute__((address_space(3))) void*)(l), 16, 0, 0)

__device__ __forceinline__ unsigned short f2bf(float x) {
    union { float f; unsigned u; } v; v.f = x;
    unsigned r = (v.u + 0x7FFF + ((v.u >> 16) & 1)) >> 16;
    return (unsigned short)r;
}

// ---------------- Kernel 1: Wc[o][40] = sum_e coefs*mask (cols 0..31 = R0, 32..39 = R1)
__global__ __launch_bounds__(256) void k_wsum(const float* __restrict__ c0,
                                              const float* __restrict__ c1,
                                              const int* __restrict__ m0,
                                              const int* __restrict__ m1,
                                              float* __restrict__ Wc) {
    int idx = blockIdx.x * 256 + threadIdx.x;
    if (idx >= 4096 * 40) return;
    int o = idx / 40, c = idx % 40;
    float s = 0.f;
    if (c < 32) {
        #pragma unroll
        for (int e = 0; e < 3; ++e) {
            int i = (e * 4096 + o) * 32 + c;
            s += c0[i] * (m0[i] != 0 ? 1.f : 0.f);
        }
    } else {
        int r = c - 32;
        #pragma unroll
        for (int e = 0; e < 3; ++e) {
            int i = (e * 4096 + o) * 8 + r;
            s += c1[i] * (m1[i] != 0 ? 1.f : 0.f);
        }
    }
    Wc[idx] = s;
}

// ---------------- Kernel 2: G[t][40] = 0.5 * (F @ Wc)[t][:]
// Block: 16 t-values, 256 threads = 16 f_slots x 4 t-groups(4t) x 4 r-groups(10r).
__global__ __launch_bounds__(256) void k_gmat(const float* __restrict__ Wc,
                                              float* __restrict__ G) {
    __shared__ float lds[10240];  // staging: 128 f-rows x 80 floats; reused for reduction
    int tid = threadIdx.x;
    int t_base = blockIdx.x * 16;
    int f_slot = tid & 15;
    int tg = (tid >> 4) & 3;
    int rg = tid >> 6;
    float acc[4][10];
    #pragma unroll
    for (int a = 0; a < 4; ++a)
        #pragma unroll
        for (int b = 0; b < 10; ++b) acc[a][b] = 0.f;

    for (int ch = 0; ch < 16; ++ch) {
        __syncthreads();
        // stage 128 f-rows: row f_local <- Wc[(2f-1)*40 .. +80) (cos row || sin row)
        #pragma unroll
        for (int j = 0; j < 10; ++j) {
            int idx = tid + j * 256;        // 0..2559 float4 slots
            int row = idx / 20;
            int v = idx % 20;
            int f = ch * 128 + row;
            f32x4 val = {0.f, 0.f, 0.f, 0.f};
            if (f >= 1) val = *(const f32x4*)(Wc + (2 * f - 1) * 40 + v * 4);
            *(f32x4*)(lds + row * 80 + v * 4) = val;
        }
        __syncthreads();
        #pragma unroll
        for (int j2 = 0; j2 < 8; ++j2) {
            int f_local = f_slot + 16 * j2;
            int f = ch * 128 + f_local;
            float cs[4], sn[4];
            #pragma unroll
            for (int tt = 0; tt < 4; ++tt) {
                int t = t_base + tg * 4 + tt;
                int ph = (f * t) & 4095;                    // exact phase mod 2pi
                float rev = (float)ph * (1.0f / 4096.0f);   // revolutions, exact
                cs[tt] = __builtin_amdgcn_cosf(rev);        // cos(2*pi*rev)
                sn[tt] = __builtin_amdgcn_sinf(rev);
            }
            const float* Lc = lds + f_local * 80 + rg * 10;
            const float* Ls = Lc + 40;
            #pragma unroll
            for (int rr = 0; rr < 10; ++rr) {
                float wc = Lc[rr], ws = Ls[rr];
                #pragma unroll
                for (int tt = 0; tt < 4; ++tt)
                    acc[tt][rr] += cs[tt] * wc + sn[tt] * ws;
            }
        }
    }
    __syncthreads();
    #pragma unroll
    for (int tt = 0; tt < 4; ++tt)
        #pragma unroll
        for (int rr = 0; rr < 10; ++rr)
            lds[tid * 40 + tt * 10 + rr] = acc[tt][rr];
    __syncthreads();
    for (int oi = tid; oi < 640; oi += 256) {
        int t_local = oi / 40, rc = oi % 40;
        int tg2 = t_local >> 2, tsub = t_local & 3;
        int rg2 = rc / 10, rsub = rc % 10;
        float s = 0.f;
        #pragma unroll
        for (int fs = 0; fs < 16; ++fs)
            s += lds[(fs + tg2 * 16 + rg2 * 64) * 40 + tsub * 10 + rsub];
        int t = t_base + t_local;
        float dc = Wc[rc];
        float ny = Wc[4095 * 40 + rc];
        float sign = (t & 1) ? -1.f : 1.f;
        // y[t] = sqrt(2/n)*pairsum + (c0 + (-1)^t c_{n-1})/sqrt(n);  n=4096; x0.5 SCALING
        float g = 0.5f * (0.0220970869120796f * s + (dc + sign * ny) * (1.0f / 64.0f));
        G[t * 40 + rc] = g;
    }
}

// ---------------- Kernel 3: Wcomb[t][d] (bf16) = W_base[t][d] + sum_k G[t][k]*E[k][d]
// Tile: 32 t x 256 d per block.
__global__ __launch_bounds__(256) void k_wcomb(const float* __restrict__ Wb,
                                               const float* __restrict__ enc0,
                                               const float* __restrict__ enc1,
                                               const float* __restrict__ G,
                                               unsigned short* __restrict__ Wcb) {
    __shared__ float ldsE[40 * 256];
    __shared__ float ldsG[32 * 40];
    int tid = threadIdx.x;
    int d0 = blockIdx.x * 256;
    int t0 = blockIdx.y * 32;
    #pragma unroll
    for (int j = 0; j < 10; ++j) {
        int idx = tid + j * 256;   // float4 slots, 40 rows x 64 slots
        int k = idx / 64, v = idx % 64;
        const float* src = (k < 32) ? (enc0 + (size_t)k * 4096) : (enc1 + (size_t)(k - 32) * 4096);
        *(f32x4*)(ldsE + k * 256 + v * 4) = *(const f32x4*)(src + d0 + v * 4);
    }
    #pragma unroll
    for (int j = 0; j < 5; ++j) {
        int idx = tid + j * 256;   // 0..1279
        ldsG[idx] = G[(size_t)(t0 + idx / 40) * 40 + (idx % 40)];
    }
    __syncthreads();
    int dg = tid & 31, tg = tid >> 5;
    f32x4 a0[4], a1[4];
    #pragma unroll
    for (int tt = 0; tt < 4; ++tt) { a0[tt] = (f32x4){0,0,0,0}; a1[tt] = (f32x4){0,0,0,0}; }
    #pragma unroll 8
    for (int r = 0; r < 40; ++r) {
        f32x4 e0 = *(const f32x4*)(ldsE + r * 256 + dg * 8);
        f32x4 e1 = *(const f32x4*)(ldsE + r * 256 + dg * 8 + 4);
        #pragma unroll
        for (int tt = 0; tt < 4; ++tt) {
            float g = ldsG[(tg * 4 + tt) * 40 + r];
            a0[tt] += g * e0;
            a1[tt] += g * e1;
        }
    }
    #pragma unroll
    for (int tt = 0; tt < 4; ++tt) {
        int t = t0 + tg * 4 + tt;
        int d = d0 + dg * 8;
        f32x4 w0 = *(const f32x4*)(Wb + (size_t)t * 4096 + d);
        f32x4 w1 = *(const f32x4*)(Wb + (size_t)t * 4096 + d + 4);
        f32x4 r0 = a0[tt] + w0, r1 = a1[tt] + w1;
        u16x8 o;
        o[0] = f2bf(r0[0]); o[1] = f2bf(r0[1]); o[2] = f2bf(r0[2]); o[3] = f2bf(r0[3]);
        o[4] = f2bf(r1[0]); o[5] = f2bf(r1[1]); o[6] = f2bf(r1[2]); o[7] = f2bf(r1[3]);
        *(u16x8*)(Wcb + (size_t)t * 4096 + d) = o;
    }
}

// ---------------- Kernel 4: x fp32 -> bf16
__global__ __launch_bounds__(256) void k_cvtx(const float* __restrict__ x,
                                              unsigned short* __restrict__ xb) {
    int idx = blockIdx.x * 256 + threadIdx.x;   // one per 8 elements; 4194304 total
    f32x4 f0 = ((const f32x4*)x)[(size_t)idx * 2];
    f32x4 f1 = ((const f32x4*)x)[(size_t)idx * 2 + 1];
    u16x8 o;
    o[0] = f2bf(f0[0]); o[1] = f2bf(f0[1]); o[2] = f2bf(f0[2]); o[3] = f2bf(f0[3]);
    o[4] = f2bf(f1[0]); o[5] = f2bf(f1[1]); o[6] = f2bf(f1[2]); o[7] = f2bf(f1[3]);
    *(u16x8*)(xb + (size_t)idx * 8) = o;
}

// ---------------- Kernel 5: C[8192][4096] = A[8192][4096] @ B[4096][4096]^T + bias
// A, B bf16 row-major (B in [n][k] form). 128x128 tile, BK=64, 4 waves 2x2, 4x4 MFMA frags.
__global__ __launch_bounds__(256) void k_gemm(const unsigned short* __restrict__ A,
                                              const unsigned short* __restrict__ B,
                                              const float* __restrict__ bias,
                                              float* __restrict__ C) {
    __shared__ short As[128 * 64];
    __shared__ short Bs[128 * 64];
    int tid = threadIdx.x;
    int lane = tid & 63, w = tid >> 6;
    int m0 = blockIdx.y * 128, n0 = blockIdx.x * 128;
    int wm = w >> 1, wn = w & 1;
    int lr = lane & 15, q = lane >> 4;

    f32x4 acc[4][4];
    #pragma unroll
    for (int i = 0; i < 4; ++i)
        #pragma unroll
        for (int j = 0; j < 4; ++j) acc[i][j] = (f32x4){0.f, 0.f, 0.f, 0.f};

    // staging base: wave w covers tile rows [w*32, w*32+32); lane -> (row = l/8, col8 = l%8)
    const unsigned short* Ab = A + (size_t)(m0 + w * 32 + (lane >> 3)) * 4096 + (lane & 7) * 8;
    const unsigned short* Bb = B + (size_t)(n0 + w * 32 + (lane >> 3)) * 4096 + (lane & 7) * 8;

    for (int kt = 0; kt < 4096; kt += 64) {
        __syncthreads();  // previous compute done before overwriting LDS
        #pragma unroll
        for (int i = 0; i < 4; ++i) {
            GL2LDS(Ab + (size_t)(i * 8) * 4096 + kt, &As[(w * 32 + i * 8) * 64]);
            GL2LDS(Bb + (size_t)(i * 8) * 4096 + kt, &Bs[(w * 32 + i * 8) * 64]);
        }
        __syncthreads();  // staging drained (vmcnt(0) before barrier)
        #pragma unroll
        for (int ks = 0; ks < 2; ++ks) {
            bf16x8 af[4], bfr[4];
            #pragma unroll
            for (int i = 0; i < 4; ++i)
                af[i] = *(const bf16x8*)&As[(wm * 64 + i * 16 + lr) * 64 + ks * 32 + q * 8];
            #pragma unroll
            for (int j = 0; j < 4; ++j)
                bfr[j] = *(const bf16x8*)&Bs[(wn * 64 + j * 16 + lr) * 64 + ks * 32 + q * 8];
            #pragma unroll
            for (int i = 0; i < 4; ++i)
                #pragma unroll
                for (int j = 0; j < 4; ++j)
                    acc[i][j] = __builtin_amdgcn_mfma_f32_16x16x32_bf16(af[i], bfr[j], acc[i][j], 0, 0, 0);
        }
    }

    float bv[4];
    #pragma unroll
    for (int j = 0; j < 4; ++j) bv[j] = bias[n0 + wn * 64 + j * 16 + lr];
    #pragma unroll
    for (int i = 0; i < 4; ++i) {
        int rbase = m0 + wm * 64 + i * 16 + q * 4;
        #pragma unroll
        for (int r = 0; r < 4; ++r) {
            float* crow = C + (size_t)(rbase + r) * 4096 + n0 + wn * 64 + lr;
            #pragma unroll
            for (int j = 0; j < 4; ++j)
                crow[j * 16] = acc[i][j][r] + bv[j];
        }
    }
}

extern "C" void kernel_launch(void* const* d_in, const int* in_sizes, int n_in,
                              void* d_out, int out_size, void* d_ws, size_t ws_size,
                              hipStream_t stream) {
    const float* x   = (const float*)d_in[0];   // [4,2048,4096]
    const float* Wb  = (const float*)d_in[1];   // [4096,4096]
    const float* bb  = (const float*)d_in[2];   // [4096]
    const float* e0  = (const float*)d_in[3];   // [32,4096]
    const float* e1  = (const float*)d_in[4];   // [8,4096]
    const float* c0  = (const float*)d_in[5];   // [3,4096,32]
    const float* c1  = (const float*)d_in[6];   // [3,4096,8]
    const int*   m0  = (const int*)d_in[7];     // [3,4096,32] bool->int32
    const int*   m1  = (const int*)d_in[8];     // [3,4096,8]
    float* out = (float*)d_out;                 // [4,2048,4096]

    char* ws = (char*)d_ws;
    unsigned short* xb  = (unsigned short*)ws;              // 67108864 B
    float* Wc           = (float*)(ws + 67108864);          // 655360 B
    float* G            = (float*)(ws + 67764224);          // 655360 B
    unsigned short* Wcb = (unsigned short*)(ws + 68419584); // 33554432 B

    k_wsum <<<640, 256, 0, stream>>>(c0, c1, m0, m1, Wc);
    k_gmat <<<256, 256, 0, stream>>>(Wc, G);
    k_wcomb<<<dim3(16, 128), 256, 0, stream>>>(Wb, e0, e1, G, Wcb);
    k_cvtx <<<16384, 256, 0, stream>>>(x, xb);
    k_gemm <<<dim3(32, 64), 256, 0, stream>>>(xb, Wcb, bb, out);
}

// Round 2
// 705.707 us; speedup vs baseline: 1.1348x; 1.1348x over previous
//
#include <hip/hip_runtime.h>

typedef __attribute__((ext_vector_type(4))) float f32x4;
typedef __attribute__((ext_vector_type(8))) short bf16x8;
typedef __attribute__((ext_vector_type(8))) unsigned short u16x8;

#define GL2LDS(g, l) __builtin_amdgcn_global_load_lds( \
    (const __attribute__((address_space(1))) void*)(g), \
    (__attribute__((address_space(3))) void*)(l), 16, 0, 0)

__device__ __forceinline__ unsigned short f2bf(float x) {
    union { float f; unsigned u; } v; v.f = x;
    unsigned r = (v.u + 0x7FFF + ((v.u >> 16) & 1)) >> 16;
    return (unsigned short)r;
}

// ---------------- Kernel 1 (fused): blocks [0,640): Wc masked expert-sum;
// blocks [640, 17024): x fp32 -> bf16 conversion. The two are independent.
__global__ __launch_bounds__(256) void k_prep(const float* __restrict__ c0,
                                              const float* __restrict__ c1,
                                              const int* __restrict__ m0,
                                              const int* __restrict__ m1,
                                              float* __restrict__ Wc,
                                              const float* __restrict__ x,
                                              unsigned short* __restrict__ xb) {
    int b = blockIdx.x;
    if (b < 640) {
        int idx = b * 256 + threadIdx.x;
        if (idx >= 4096 * 40) return;
        int o = idx / 40, c = idx % 40;
        float s = 0.f;
        if (c < 32) {
            #pragma unroll
            for (int e = 0; e < 3; ++e) {
                int i = (e * 4096 + o) * 32 + c;
                s += c0[i] * (m0[i] != 0 ? 1.f : 0.f);
            }
        } else {
            int r = c - 32;
            #pragma unroll
            for (int e = 0; e < 3; ++e) {
                int i = (e * 4096 + o) * 8 + r;
                s += c1[i] * (m1[i] != 0 ? 1.f : 0.f);
            }
        }
        Wc[idx] = s;
    } else {
        int idx = (b - 640) * 256 + threadIdx.x;  // one per 8 elements; 4194304 total
        f32x4 f0 = ((const f32x4*)x)[(size_t)idx * 2];
        f32x4 f1 = ((const f32x4*)x)[(size_t)idx * 2 + 1];
        u16x8 o;
        o[0] = f2bf(f0[0]); o[1] = f2bf(f0[1]); o[2] = f2bf(f0[2]); o[3] = f2bf(f0[3]);
        o[4] = f2bf(f1[0]); o[5] = f2bf(f1[1]); o[6] = f2bf(f1[2]); o[7] = f2bf(f1[3]);
        *(u16x8*)(xb + (size_t)idx * 8) = o;
    }
}

// ---------------- Kernel 2: G[t][40] = 0.5 * (F @ Wc)[t][:]
// Block: 16 t-values, 256 threads = 16 f_slots x 4 t-groups(4t) x 4 r-groups(10r).
// LDS row stride 84 floats (84*4 B): stride%128B != 0 -> 2-way max on cos/sin reads.
__global__ __launch_bounds__(256) void k_gmat(const float* __restrict__ Wc,
                                              float* __restrict__ G) {
    __shared__ float lds[10752];  // staging: 128 f-rows x 84 floats; reused for reduction
    int tid = threadIdx.x;
    int t_base = blockIdx.x * 16;
    int f_slot = tid & 15;
    int tg = (tid >> 4) & 3;
    int rg = tid >> 6;
    float acc[4][10];
    #pragma unroll
    for (int a = 0; a < 4; ++a)
        #pragma unroll
        for (int b = 0; b < 10; ++b) acc[a][b] = 0.f;

    for (int ch = 0; ch < 16; ++ch) {
        __syncthreads();
        // stage 128 f-rows: row f_local <- Wc[(2f-1)*40 .. +80) (cos row || sin row)
        #pragma unroll
        for (int j = 0; j < 10; ++j) {
            int idx = tid + j * 256;        // 0..2559 float4 slots
            int row = idx / 20;
            int v = idx % 20;
            int f = ch * 128 + row;
            f32x4 val = {0.f, 0.f, 0.f, 0.f};
            if (f >= 1) val = *(const f32x4*)(Wc + (2 * f - 1) * 40 + v * 4);
            *(f32x4*)(lds + row * 84 + v * 4) = val;
        }
        __syncthreads();
        #pragma unroll
        for (int j2 = 0; j2 < 8; ++j2) {
            int f_local = f_slot + 16 * j2;
            int f = ch * 128 + f_local;
            float cs[4], sn[4];
            #pragma unroll
            for (int tt = 0; tt < 4; ++tt) {
                int t = t_base + tg * 4 + tt;
                int ph = (f * t) & 4095;                    // exact phase mod 2pi
                float rev = (float)ph * (1.0f / 4096.0f);   // revolutions, exact
                cs[tt] = __builtin_amdgcn_cosf(rev);        // cos(2*pi*rev)
                sn[tt] = __builtin_amdgcn_sinf(rev);
            }
            const float* Lc = lds + f_local * 84 + rg * 10;
            const float* Ls = Lc + 40;
            #pragma unroll
            for (int rr = 0; rr < 10; ++rr) {
                float wc = Lc[rr], ws = Ls[rr];
                #pragma unroll
                for (int tt = 0; tt < 4; ++tt)
                    acc[tt][rr] += cs[tt] * wc + sn[tt] * ws;
            }
        }
    }
    __syncthreads();
    #pragma unroll
    for (int tt = 0; tt < 4; ++tt)
        #pragma unroll
        for (int rr = 0; rr < 10; ++rr)
            lds[tid * 40 + tt * 10 + rr] = acc[tt][rr];
    __syncthreads();
    for (int oi = tid; oi < 640; oi += 256) {
        int t_local = oi / 40, rc = oi % 40;
        int tg2 = t_local >> 2, tsub = t_local & 3;
        int rg2 = rc / 10, rsub = rc % 10;
        float s = 0.f;
        #pragma unroll
        for (int fs = 0; fs < 16; ++fs)
            s += lds[(fs + tg2 * 16 + rg2 * 64) * 40 + tsub * 10 + rsub];
        int t = t_base + t_local;
        float dc = Wc[rc];
        float ny = Wc[4095 * 40 + rc];
        float sign = (t & 1) ? -1.f : 1.f;
        // y[t] = sqrt(2/n)*pairsum + (c0 + (-1)^t c_{n-1})/sqrt(n);  n=4096; x0.5 SCALING
        float g = 0.5f * (0.0220970869120796f * s + (dc + sign * ny) * (1.0f / 64.0f));
        G[t * 40 + rc] = g;
    }
}

// ---------------- Kernel 3: Wcomb[t][d] (bf16) = W_base[t][d] + sum_k G[t][k]*E[k][d]
// Tile: 32 t x 256 d per block.
__global__ __launch_bounds__(256) void k_wcomb(const float* __restrict__ Wb,
                                               const float* __restrict__ enc0,
                                               const float* __restrict__ enc1,
                                               const float* __restrict__ G,
                                               unsigned short* __restrict__ Wcb) {
    __shared__ float ldsE[40 * 256];
    __shared__ float ldsG[32 * 40];
    int tid = threadIdx.x;
    int d0 = blockIdx.x * 256;
    int t0 = blockIdx.y * 32;
    #pragma unroll
    for (int j = 0; j < 10; ++j) {
        int idx = tid + j * 256;   // float4 slots, 40 rows x 64 slots
        int k = idx / 64, v = idx % 64;
        const float* src = (k < 32) ? (enc0 + (size_t)k * 4096) : (enc1 + (size_t)(k - 32) * 4096);
        *(f32x4*)(ldsE + k * 256 + v * 4) = *(const f32x4*)(src + d0 + v * 4);
    }
    #pragma unroll
    for (int j = 0; j < 5; ++j) {
        int idx = tid + j * 256;   // 0..1279
        ldsG[idx] = G[(size_t)(t0 + idx / 40) * 40 + (idx % 40)];
    }
    __syncthreads();
    int dg = tid & 31, tg = tid >> 5;
    f32x4 a0[4], a1[4];
    #pragma unroll
    for (int tt = 0; tt < 4; ++tt) { a0[tt] = (f32x4){0,0,0,0}; a1[tt] = (f32x4){0,0,0,0}; }
    #pragma unroll 8
    for (int r = 0; r < 40; ++r) {
        f32x4 e0 = *(const f32x4*)(ldsE + r * 256 + dg * 8);
        f32x4 e1 = *(const f32x4*)(ldsE + r * 256 + dg * 8 + 4);
        #pragma unroll
        for (int tt = 0; tt < 4; ++tt) {
            float g = ldsG[(tg * 4 + tt) * 40 + r];
            a0[tt] += g * e0;
            a1[tt] += g * e1;
        }
    }
    #pragma unroll
    for (int tt = 0; tt < 4; ++tt) {
        int t = t0 + tg * 4 + tt;
        int d = d0 + dg * 8;
        f32x4 w0 = *(const f32x4*)(Wb + (size_t)t * 4096 + d);
        f32x4 w1 = *(const f32x4*)(Wb + (size_t)t * 4096 + d + 4);
        f32x4 r0 = a0[tt] + w0, r1 = a1[tt] + w1;
        u16x8 o;
        o[0] = f2bf(r0[0]); o[1] = f2bf(r0[1]); o[2] = f2bf(r0[2]); o[3] = f2bf(r0[3]);
        o[4] = f2bf(r1[0]); o[5] = f2bf(r1[1]); o[6] = f2bf(r1[2]); o[7] = f2bf(r1[3]);
        *(u16x8*)(Wcb + (size_t)t * 4096 + d) = o;
    }
}

// ---------------- Kernel 4: C[8192][4096] = A[8192][4096] @ B[4096][4096]^T + bias
// A, B bf16 row-major (B in [n][k] form). 128x128 tile, BK=64, 4 waves 2x2, 4x4 MFMA frags.
// LDS XOR swizzle: slot (row, c) holds global (row, c ^ (row&7)) where c = 16B-group.
// Implemented by permuting the GLOBAL source column per lane (stays inside one 128B
// segment -> coalescing intact; global_load_lds dest stays base+lane*16).
// Fragment reads then hit bank quads spread over all 32 banks, 2 lanes/bank = free.
__global__ __launch_bounds__(256) void k_gemm(const unsigned short* __restrict__ A,
                                              const unsigned short* __restrict__ B,
                                              const float* __restrict__ bias,
                                              float* __restrict__ C) {
    __shared__ short As[128 * 64];
    __shared__ short Bs[128 * 64];
    int tid = threadIdx.x;
    int lane = tid & 63, w = tid >> 6;
    int m0 = blockIdx.y * 128, n0 = blockIdx.x * 128;
    int wm = w >> 1, wn = w & 1;
    int lr = lane & 15, q = lane >> 4;

    f32x4 acc[4][4];
    #pragma unroll
    for (int i = 0; i < 4; ++i)
        #pragma unroll
        for (int j = 0; j < 4; ++j) acc[i][j] = (f32x4){0.f, 0.f, 0.f, 0.f};

    // staging: lane -> row (lane>>3) of the 8-row group, swizzled 16B column group
    int rw = lane >> 3;                 // row within 8-row group == row&7 (groups 8-aligned)
    int cg = (lane & 7) ^ rw;           // XOR-swizzled column group
    const unsigned short* Ab = A + (size_t)(m0 + w * 32 + rw) * 4096 + cg * 8;
    const unsigned short* Bb = B + (size_t)(n0 + w * 32 + rw) * 4096 + cg * 8;

    for (int kt = 0; kt < 4096; kt += 64) {
        __syncthreads();  // previous compute done before overwriting LDS
        #pragma unroll
        for (int i = 0; i < 4; ++i) {
            GL2LDS(Ab + (size_t)(i * 8) * 4096 + kt, &As[(w * 32 + i * 8) * 64]);
            GL2LDS(Bb + (size_t)(i * 8) * 4096 + kt, &Bs[(w * 32 + i * 8) * 64]);
        }
        __syncthreads();  // staging drained (vmcnt(0) before barrier)
        int sw = lr & 7;  // == row&7 for all fragment rows below
        #pragma unroll
        for (int ks = 0; ks < 2; ++ks) {
            bf16x8 af[4], bfr[4];
            #pragma unroll
            for (int i = 0; i < 4; ++i)
                af[i] = *(const bf16x8*)&As[(wm * 64 + i * 16 + lr) * 64 + (((ks * 4 + q) ^ sw) * 8)];
            #pragma unroll
            for (int j = 0; j < 4; ++j)
                bfr[j] = *(const bf16x8*)&Bs[(wn * 64 + j * 16 + lr) * 64 + (((ks * 4 + q) ^ sw) * 8)];
            #pragma unroll
            for (int i = 0; i < 4; ++i)
                #pragma unroll
                for (int j = 0; j < 4; ++j)
                    acc[i][j] = __builtin_amdgcn_mfma_f32_16x16x32_bf16(af[i], bfr[j], acc[i][j], 0, 0, 0);
        }
    }

    float bv[4];
    #pragma unroll
    for (int j = 0; j < 4; ++j) bv[j] = bias[n0 + wn * 64 + j * 16 + lr];
    #pragma unroll
    for (int i = 0; i < 4; ++i) {
        int rbase = m0 + wm * 64 + i * 16 + q * 4;
        #pragma unroll
        for (int r = 0; r < 4; ++r) {
            float* crow = C + (size_t)(rbase + r) * 4096 + n0 + wn * 64 + lr;
            #pragma unroll
            for (int j = 0; j < 4; ++j)
                crow[j * 16] = acc[i][j][r] + bv[j];
        }
    }
}

extern "C" void kernel_launch(void* const* d_in, const int* in_sizes, int n_in,
                              void* d_out, int out_size, void* d_ws, size_t ws_size,
                              hipStream_t stream) {
    const float* x   = (const float*)d_in[0];   // [4,2048,4096]
    const float* Wb  = (const float*)d_in[1];   // [4096,4096]
    const float* bb  = (const float*)d_in[2];   // [4096]
    const float* e0  = (const float*)d_in[3];   // [32,4096]
    const float* e1  = (const float*)d_in[4];   // [8,4096]
    const float* c0  = (const float*)d_in[5];   // [3,4096,32]
    const float* c1  = (const float*)d_in[6];   // [3,4096,8]
    const int*   m0  = (const int*)d_in[7];     // [3,4096,32] bool->int32
    const int*   m1  = (const int*)d_in[8];     // [3,4096,8]
    float* out = (float*)d_out;                 // [4,2048,4096]

    char* ws = (char*)d_ws;
    unsigned short* xb  = (unsigned short*)ws;              // 67108864 B
    float* Wc           = (float*)(ws + 67108864);          // 655360 B
    float* G            = (float*)(ws + 67764224);          // 655360 B
    unsigned short* Wcb = (unsigned short*)(ws + 68419584); // 33554432 B

    k_prep <<<17024, 256, 0, stream>>>(c0, c1, m0, m1, Wc, x, xb);
    k_gmat <<<256, 256, 0, stream>>>(Wc, G);
    k_wcomb<<<dim3(16, 128), 256, 0, stream>>>(Wb, e0, e1, G, Wcb);
    k_gemm <<<dim3(32, 64), 256, 0, stream>>>(xb, Wcb, bb, out);
}

// Round 3
// 642.111 us; speedup vs baseline: 1.2472x; 1.0990x over previous
//
#include <hip/hip_runtime.h>

typedef __attribute__((ext_vector_type(2))) float f32x2;
typedef __attribute__((ext_vector_type(4))) float f32x4;
typedef __attribute__((ext_vector_type(16))) float f32x16;
typedef __attribute__((ext_vector_type(8))) short bf16x8;
typedef __attribute__((ext_vector_type(8))) unsigned short u16x8;

#define GL2LDS(g, l) __builtin_amdgcn_global_load_lds( \
    (const __attribute__((address_space(1))) void*)(g), \
    (__attribute__((address_space(3))) void*)(l), 16, 0, 0)

__device__ __forceinline__ unsigned short f2bf(float x) {
    union { float f; unsigned u; } v; v.f = x;
    unsigned r = (v.u + 0x7FFF + ((v.u >> 16) & 1)) >> 16;
    return (unsigned short)r;
}

// ---------------- Kernel 1 (fused): blocks [0,640): Wc masked expert-sum;
// blocks [640, 17024): x fp32 -> bf16 conversion. The two are independent.
__global__ __launch_bounds__(256) void k_prep(const float* __restrict__ c0,
                                              const float* __restrict__ c1,
                                              const int* __restrict__ m0,
                                              const int* __restrict__ m1,
                                              float* __restrict__ Wc,
                                              const float* __restrict__ x,
                                              unsigned short* __restrict__ xb) {
    int b = blockIdx.x;
    if (b < 640) {
        int idx = b * 256 + threadIdx.x;
        if (idx >= 4096 * 40) return;
        int o = idx / 40, c = idx % 40;
        float s = 0.f;
        if (c < 32) {
            #pragma unroll
            for (int e = 0; e < 3; ++e) {
                int i = (e * 4096 + o) * 32 + c;
                s += c0[i] * (m0[i] != 0 ? 1.f : 0.f);
            }
        } else {
            int r = c - 32;
            #pragma unroll
            for (int e = 0; e < 3; ++e) {
                int i = (e * 4096 + o) * 8 + r;
                s += c1[i] * (m1[i] != 0 ? 1.f : 0.f);
            }
        }
        Wc[idx] = s;
    } else {
        int idx = (b - 640) * 256 + threadIdx.x;  // one per 8 elements; 4194304 total
        f32x4 f0 = ((const f32x4*)x)[(size_t)idx * 2];
        f32x4 f1 = ((const f32x4*)x)[(size_t)idx * 2 + 1];
        u16x8 o;
        o[0] = f2bf(f0[0]); o[1] = f2bf(f0[1]); o[2] = f2bf(f0[2]); o[3] = f2bf(f0[3]);
        o[4] = f2bf(f1[0]); o[5] = f2bf(f1[1]); o[6] = f2bf(f1[2]); o[7] = f2bf(f1[3]);
        *(u16x8*)(xb + (size_t)idx * 8) = o;
    }
}

// ---------------- Kernel 2: G[t][40] = 0.5 * (F @ Wc)[t][:]
// Block: 8 t-values, 256 threads = 32 f_slots x 2 t-groups(4t) x 4 r-groups(10r).
// 512 blocks -> 2 blocks/CU (was 1) for latency hiding.
__global__ __launch_bounds__(256) void k_gmat(const float* __restrict__ Wc,
                                              float* __restrict__ G) {
    __shared__ float lds[10752];  // staging: 128 f-rows x 84 floats; reused for reduction
    int tid = threadIdx.x;
    int t_base = blockIdx.x * 8;
    int f_slot = tid & 31;
    int tg = (tid >> 5) & 1;
    int rg = tid >> 6;
    float acc[4][10];
    #pragma unroll
    for (int a = 0; a < 4; ++a)
        #pragma unroll
        for (int b = 0; b < 10; ++b) acc[a][b] = 0.f;

    for (int ch = 0; ch < 16; ++ch) {
        __syncthreads();
        // stage 128 f-rows: row f_local <- Wc[(2f-1)*40 .. +80) (cos row || sin row)
        #pragma unroll
        for (int j = 0; j < 10; ++j) {
            int idx = tid + j * 256;        // 0..2559 float4 slots
            int row = idx / 20;
            int v = idx % 20;
            int f = ch * 128 + row;
            f32x4 val = {0.f, 0.f, 0.f, 0.f};
            if (f >= 1) val = *(const f32x4*)(Wc + (2 * f - 1) * 40 + v * 4);
            *(f32x4*)(lds + row * 84 + v * 4) = val;
        }
        __syncthreads();
        #pragma unroll
        for (int j2 = 0; j2 < 4; ++j2) {
            int f_local = f_slot + 32 * j2;
            int f = ch * 128 + f_local;
            float cs[4], sn[4];
            #pragma unroll
            for (int tt = 0; tt < 4; ++tt) {
                int t = t_base + tg * 4 + tt;
                int ph = (f * t) & 4095;                    // exact phase mod 2pi
                float rev = (float)ph * (1.0f / 4096.0f);   // revolutions, exact
                cs[tt] = __builtin_amdgcn_cosf(rev);        // cos(2*pi*rev)
                sn[tt] = __builtin_amdgcn_sinf(rev);
            }
            const float* Lc = lds + f_local * 84 + rg * 10;
            const float* Ls = Lc + 40;
            #pragma unroll
            for (int rr = 0; rr < 10; ++rr) {
                float wc = Lc[rr], ws = Ls[rr];
                #pragma unroll
                for (int tt = 0; tt < 4; ++tt)
                    acc[tt][rr] += cs[tt] * wc + sn[tt] * ws;
            }
        }
    }
    __syncthreads();
    #pragma unroll
    for (int tt = 0; tt < 4; ++tt)
        #pragma unroll
        for (int rr = 0; rr < 10; ++rr)
            lds[tid * 40 + tt * 10 + rr] = acc[tt][rr];
    __syncthreads();
    for (int oi = tid; oi < 320; oi += 256) {
        int t_local = oi / 40, rc = oi % 40;
        int tg2 = t_local >> 2, tsub = t_local & 3;
        int rg2 = rc / 10, rsub = rc % 10;
        float s = 0.f;
        #pragma unroll
        for (int fs = 0; fs < 32; ++fs)
            s += lds[(fs + tg2 * 32 + rg2 * 64) * 40 + tsub * 10 + rsub];
        int t = t_base + t_local;
        float dc = Wc[rc];
        float ny = Wc[4095 * 40 + rc];
        float sign = (t & 1) ? -1.f : 1.f;
        // y[t] = sqrt(2/n)*pairsum + (c0 + (-1)^t c_{n-1})/sqrt(n);  n=4096; x0.5 SCALING
        float g = 0.5f * (0.0220970869120796f * s + (dc + sign * ny) * (1.0f / 64.0f));
        G[t * 40 + rc] = g;
    }
}

// ---------------- Kernel 3: Wcomb[t][d] (bf16) = W_base[t][d] + sum_k G[t][k]*E[k][d]
// Tile: 32 t x 256 d per block. LDS reads as f32x2 at 8B lane stride: banks
// (dg*2)%32 -> 2 lanes/bank-pair + tg-broadcast = conflict-free (was 8-way on b128).
__global__ __launch_bounds__(256) void k_wcomb(const float* __restrict__ Wb,
                                               const float* __restrict__ enc0,
                                               const float* __restrict__ enc1,
                                               const float* __restrict__ G,
                                               unsigned short* __restrict__ Wcb) {
    __shared__ float ldsE[40 * 256];
    __shared__ float ldsG[32 * 40];
    int tid = threadIdx.x;
    int d0 = blockIdx.x * 256;
    int t0 = blockIdx.y * 32;
    #pragma unroll
    for (int j = 0; j < 10; ++j) {
        int idx = tid + j * 256;   // float4 slots, 40 rows x 64 slots
        int k = idx / 64, v = idx % 64;
        const float* src = (k < 32) ? (enc0 + (size_t)k * 4096) : (enc1 + (size_t)(k - 32) * 4096);
        *(f32x4*)(ldsE + k * 256 + v * 4) = *(const f32x4*)(src + d0 + v * 4);
    }
    #pragma unroll
    for (int j = 0; j < 5; ++j) {
        int idx = tid + j * 256;   // 0..1279
        ldsG[idx] = G[(size_t)(t0 + idx / 40) * 40 + (idx % 40)];
    }
    __syncthreads();
    int dg = tid & 31, tg = tid >> 5;
    // thread covers d-cols {s*64 + dg*2, +1} for s=0..3, t rows t0+tg*4..+3
    f32x2 a[4][4];  // [s][tt]
    #pragma unroll
    for (int s = 0; s < 4; ++s)
        #pragma unroll
        for (int tt = 0; tt < 4; ++tt) a[s][tt] = (f32x2){0.f, 0.f};
    #pragma unroll 8
    for (int r = 0; r < 40; ++r) {
        f32x2 e[4];
        #pragma unroll
        for (int s = 0; s < 4; ++s)
            e[s] = *(const f32x2*)(ldsE + r * 256 + s * 64 + dg * 2);
        #pragma unroll
        for (int tt = 0; tt < 4; ++tt) {
            float g = ldsG[(tg * 4 + tt) * 40 + r];
            #pragma unroll
            for (int s = 0; s < 4; ++s)
                a[s][tt] += g * e[s];
        }
    }
    #pragma unroll
    for (int tt = 0; tt < 4; ++tt) {
        int t = t0 + tg * 4 + tt;
        #pragma unroll
        for (int s = 0; s < 4; ++s) {
            int d = d0 + s * 64 + dg * 2;
            f32x2 wv = *(const f32x2*)(Wb + (size_t)t * 4096 + d);
            f32x2 rv = a[s][tt] + wv;
            unsigned short lo = f2bf(rv[0]), hi = f2bf(rv[1]);
            *(unsigned*)(Wcb + (size_t)t * 4096 + d) = (unsigned)lo | ((unsigned)hi << 16);
        }
    }
}

// ---------------- Kernel 4: C[8192][4096] = A[8192][4096] @ B[4096][4096]^T + bias
// 32x32x16 MFMA: wave covers 64x64 via 2x2 f32x16 frags -> half the MFMA issue count
// of the 16x16x32 version at the same FLOPs (ubench 2382 vs 2075 TF).
// LDS XOR swizzle (verified 0 conflicts in R2): slot (row,c) holds global (row, c^(row&7)).
__global__ __launch_bounds__(256) void k_gemm(const unsigned short* __restrict__ A,
                                              const unsigned short* __restrict__ B,
                                              const float* __restrict__ bias,
                                              float* __restrict__ C) {
    __shared__ short As[128 * 64];
    __shared__ short Bs[128 * 64];
    int tid = threadIdx.x;
    int lane = tid & 63, w = tid >> 6;
    int m0 = blockIdx.y * 128, n0 = blockIdx.x * 128;
    int wm = w >> 1, wn = w & 1;
    int col = lane & 31;   // m/n index within a 32-wide fragment
    int hi = lane >> 5;    // k-half selector
    int sw = col & 7;      // swizzle key (== row&7 for all fragment rows)

    f32x16 acc[2][2];
    #pragma unroll
    for (int i = 0; i < 2; ++i)
        #pragma unroll
        for (int j = 0; j < 2; ++j)
            #pragma unroll
            for (int r = 0; r < 16; ++r) acc[i][j][r] = 0.f;

    // staging: lane -> row (lane>>3) of the 8-row group, XOR-swizzled 16B column group
    int rw = lane >> 3;
    int cg = (lane & 7) ^ rw;
    const unsigned short* Ab = A + (size_t)(m0 + w * 32 + rw) * 4096 + cg * 8;
    const unsigned short* Bb = B + (size_t)(n0 + w * 32 + rw) * 4096 + cg * 8;

    int aoff0 = (wm * 64 + col) * 64;        // ii=0 row base (shorts)
    int boff0 = (wn * 64 + col) * 64;

    for (int kt = 0; kt < 4096; kt += 64) {
        __syncthreads();  // previous compute done before overwriting LDS
        #pragma unroll
        for (int i = 0; i < 4; ++i) {
            GL2LDS(Ab + (size_t)(i * 8) * 4096 + kt, &As[(w * 32 + i * 8) * 64]);
            GL2LDS(Bb + (size_t)(i * 8) * 4096 + kt, &Bs[(w * 32 + i * 8) * 64]);
        }
        __syncthreads();  // staging drained (vmcnt(0) before barrier)
        #pragma unroll
        for (int ks = 0; ks < 4; ++ks) {
            int co = ((ks * 2 + hi) ^ sw) * 8;   // swizzled k-column offset (shorts)
            bf16x8 a0 = *(const bf16x8*)&As[aoff0 + co];
            bf16x8 a1 = *(const bf16x8*)&As[aoff0 + 32 * 64 + co];
            bf16x8 b0 = *(const bf16x8*)&Bs[boff0 + co];
            bf16x8 b1 = *(const bf16x8*)&Bs[boff0 + 32 * 64 + co];
            acc[0][0] = __builtin_amdgcn_mfma_f32_32x32x16_bf16(a0, b0, acc[0][0], 0, 0, 0);
            acc[0][1] = __builtin_amdgcn_mfma_f32_32x32x16_bf16(a0, b1, acc[0][1], 0, 0, 0);
            acc[1][0] = __builtin_amdgcn_mfma_f32_32x32x16_bf16(a1, b0, acc[1][0], 0, 0, 0);
            acc[1][1] = __builtin_amdgcn_mfma_f32_32x32x16_bf16(a1, b1, acc[1][1], 0, 0, 0);
        }
    }

    // C/D layout (m74/m101): col = lane&31, row = (reg&3) + 8*(reg>>2) + 4*(lane>>5)
    float bv[2];
    #pragma unroll
    for (int j = 0; j < 2; ++j) bv[j] = bias[n0 + wn * 64 + j * 32 + col];
    #pragma unroll
    for (int i = 0; i < 2; ++i)
        #pragma unroll
        for (int r = 0; r < 16; ++r) {
            int row = m0 + wm * 64 + i * 32 + (r & 3) + 8 * (r >> 2) + 4 * hi;
            float* crow = C + (size_t)row * 4096 + n0 + wn * 64 + col;
            crow[0]  = acc[i][0][r] + bv[0];
            crow[32] = acc[i][1][r] + bv[1];
        }
}

extern "C" void kernel_launch(void* const* d_in, const int* in_sizes, int n_in,
                              void* d_out, int out_size, void* d_ws, size_t ws_size,
                              hipStream_t stream) {
    const float* x   = (const float*)d_in[0];   // [4,2048,4096]
    const float* Wb  = (const float*)d_in[1];   // [4096,4096]
    const float* bb  = (const float*)d_in[2];   // [4096]
    const float* e0  = (const float*)d_in[3];   // [32,4096]
    const float* e1  = (const float*)d_in[4];   // [8,4096]
    const float* c0  = (const float*)d_in[5];   // [3,4096,32]
    const float* c1  = (const float*)d_in[6];   // [3,4096,8]
    const int*   m0  = (const int*)d_in[7];     // [3,4096,32] bool->int32
    const int*   m1  = (const int*)d_in[8];     // [3,4096,8]
    float* out = (float*)d_out;                 // [4,2048,4096]

    char* ws = (char*)d_ws;
    unsigned short* xb  = (unsigned short*)ws;              // 67108864 B
    float* Wc           = (float*)(ws + 67108864);          // 655360 B
    float* G            = (float*)(ws + 67764224);          // 655360 B
    unsigned short* Wcb = (unsigned short*)(ws + 68419584); // 33554432 B

    k_prep <<<17024, 256, 0, stream>>>(c0, c1, m0, m1, Wc, x, xb);
    k_gmat <<<512, 256, 0, stream>>>(Wc, G);
    k_wcomb<<<dim3(16, 128), 256, 0, stream>>>(Wb, e0, e1, G, Wcb);
    k_gemm <<<dim3(32, 64), 256, 0, stream>>>(xb, Wcb, bb, out);
}